// Round 4
// baseline (95.092 us; speedup 1.0000x reference)
//
#include <hip/hip_runtime.h>
#include <hip/hip_bf16.h>

#define NPIX 4096   // 64*64 pixels per batch
#define CCH  64     // channels
#define NB   8      // batch

typedef __attribute__((ext_vector_type(8)))  short short8;   // 8 bf16 MFMA A/B frag (32x32x16)
typedef __attribute__((ext_vector_type(4)))  float f32x4;
typedef __attribute__((ext_vector_type(16))) float f32x16;   // 32x32 MFMA C/D frag

#define LOG2E   1.44269504f
#define SHIFT2  17.3123405f   // 12 * log2e : P = 2^(S*log2e - SHIFT2) = e^(S-12)

// ---------------------------------------------------------------------------
// Kernel 1: fused 1x1-conv projections.
//   Q[b][i][oc] = log2e * (W1 x + b1)   (bf16 pixel-major; scaled for exp2)
//   G[b][j][oc] =         (W2 x + b2)   (bf16 pixel-major)
//   K[b][oc][j] =         (W3 x + b3)   (bf16 channel-major)
// ---------------------------------------------------------------------------
__global__ __launch_bounds__(256) void proj_kernel(
    const float* __restrict__ x,
    const float* __restrict__ W1, const float* __restrict__ b1,
    const float* __restrict__ W2, const float* __restrict__ b2,
    const float* __restrict__ W3, const float* __restrict__ b3,
    __hip_bfloat16* __restrict__ Q, __hip_bfloat16* __restrict__ G,
    __hip_bfloat16* __restrict__ K)
{
    const int b  = blockIdx.x >> 6;
    const int i0 = (blockIdx.x & 63) << 6;

    __shared__ float xs[64][65];
    __shared__ float Wt[3][64][68];

    for (int e = threadIdx.x; e < 4096; e += 256) {
        const int c = e >> 6, p = e & 63;
        xs[c][p] = x[(size_t)b * CCH * NPIX + (size_t)c * NPIX + i0 + p];
        Wt[0][e & 63][e >> 6] = W1[e];
        Wt[1][e & 63][e >> 6] = W2[e];
        Wt[2][e & 63][e >> 6] = W3[e];
    }
    __syncthreads();

    const int p = threadIdx.x & 63;
    const int g = threadIdx.x >> 6;

    float acc0[16], acc1[16], acc2[16];
    #pragma unroll
    for (int oo = 0; oo < 16; ++oo) {
        acc0[oo] = b1[g * 16 + oo];
        acc1[oo] = b2[g * 16 + oo];
        acc2[oo] = b3[g * 16 + oo];
    }

    for (int c = 0; c < 64; ++c) {
        const float xv = xs[c][p];
        const f32x4* w0 = (const f32x4*)&Wt[0][c][g * 16];
        const f32x4* w1 = (const f32x4*)&Wt[1][c][g * 16];
        const f32x4* w2 = (const f32x4*)&Wt[2][c][g * 16];
        #pragma unroll
        for (int q = 0; q < 4; ++q) {
            const f32x4 a = w0[q], bb = w1[q], cc = w2[q];
            #pragma unroll
            for (int j = 0; j < 4; ++j) {
                acc0[q * 4 + j] += a[j] * xv;
                acc1[q * 4 + j] += bb[j] * xv;
                acc2[q * 4 + j] += cc[j] * xv;
            }
        }
    }

    const int i = i0 + p;
    #pragma unroll
    for (int oo = 0; oo < 16; ++oo) {
        const int oc = g * 16 + oo;
        Q[(size_t)b * NPIX * CCH + (size_t)i * CCH + oc] = __float2bfloat16(acc0[oo] * LOG2E);
        G[(size_t)b * NPIX * CCH + (size_t)i * CCH + oc] = __float2bfloat16(acc1[oo]);
        K[(size_t)b * CCH * NPIX + (size_t)oc * NPIX + i] = __float2bfloat16(acc2[oo]);
    }
}

// ---------------------------------------------------------------------------
// Kernel 2: LDS-staged flash attention, 32x32x16 MFMA, swapped QK^T,
// in-register P (cvt_pk_bf16 + permlane32_swap), fixed-shift softmax,
// softmax denominator via ones-MFMA (no VALU row-sum), zacc C-init trick.
// Block: 4 waves x 64 rows = 256 Q-rows; j-tiles of 64, double-buffered LDS.
// 32x32x16 bf16 layouts (m74/m101-verified C/D; A/B contiguous-8k):
//   A: row=lane&31, k=8*(lane>>5)+t     B: col=lane&31, k=8*(lane>>5)+t
//   C/D: col=lane&31, row=(r&3)+8*(r>>2)+4*(lane>>5)
// Swapped QK: mfma(A=G, B=Q) -> lane holds S^T[j...][i=lane&31] (lane-local).
// ---------------------------------------------------------------------------
__device__ __forceinline__ void gload_lds16(const void* g, void* l) {
    __builtin_amdgcn_global_load_lds(
        (const __attribute__((address_space(1))) unsigned int*)g,
        (__attribute__((address_space(3))) unsigned int*)l, 16, 0, 0);
}
__device__ __forceinline__ unsigned int cvtpk_bf16(float lo, float hi) {
    unsigned int r;
    asm volatile("v_cvt_pk_bf16_f32 %0, %1, %2" : "=v"(r) : "v"(lo), "v"(hi));
    return r;
}

__global__ __launch_bounds__(256, 2) void attn_kernel(
    const __hip_bfloat16* __restrict__ Qg, const __hip_bfloat16* __restrict__ Gg,
    const __hip_bfloat16* __restrict__ Kg,
    float* __restrict__ Opart, float* __restrict__ Lpart, int split)
{
    __shared__ char lds[2][16384];      // [buf][ G 8KB | K 8KB ], XOR-swizzled rows

    const int blk   = blockIdx.x;
    const int per_b = 16 * split;
    const int b     = blk / per_b;
    const int rem   = blk - b * per_b;
    const int itile = rem / split;
    const int sp    = rem - itile * split;
    const int wave  = threadIdx.x >> 6;
    const int lane  = threadIdx.x & 63;
    const int l32   = lane & 31;
    const int hi    = lane >> 5;
    const int i0w   = itile * 256 + wave * 64;    // wave's first of 64 rows
    const int jcnt  = NPIX / split;
    const int jlo   = sp * jcnt;
    const int niter = jcnt >> 6;

    const short* Qb = (const short*)Qg + (size_t)b * NPIX * CCH;
    const char*  Gb = (const char*)(Gg + (size_t)b * NPIX * CCH);
    const char*  Kb = (const char*)(Kg + (size_t)b * CCH * NPIX);

    // Q B-frags: q[ib][ks] -> Q[i0w+ib*32+l32][16ks+8hi+t]
    short8 q[2][4];
    #pragma unroll
    for (int ib = 0; ib < 2; ++ib)
        #pragma unroll
        for (int ks = 0; ks < 4; ++ks)
            q[ib][ks] = *(const short8*)(Qb + (size_t)(i0w + ib * 32 + l32) * CCH + ks * 16 + hi * 8);

    // hoisted loop-invariant swizzled LDS byte offsets
    int gaoff[2][4], kaoff[2][4];
    #pragma unroll
    for (int jb = 0; jb < 2; ++jb) {
        const int row = jb * 32 + l32;
        #pragma unroll
        for (int ks = 0; ks < 4; ++ks)
            gaoff[jb][ks] = row * 128 + (((2 * ks + hi) ^ (row & 7)) << 4);
    }
    #pragma unroll
    for (int cb = 0; cb < 2; ++cb) {
        const int row = cb * 32 + l32;
        #pragma unroll
        for (int ks = 0; ks < 4; ++ks)
            kaoff[cb][ks] = 8192 + row * 128 + (((2 * ks + hi) ^ (row & 7)) << 4);
    }

    // hoisted constants: C-init register block (-SHIFT2) and ones A-frag
    f32x16 zacc;
    #pragma unroll
    for (int r = 0; r < 16; ++r) zacc[r] = -SHIFT2;
    short8 ones;
    #pragma unroll
    for (int t = 0; t < 8; ++t) ones[t] = (short)0x3F80;   // bf16 1.0

    f32x16 o[2][2];                      // [ib][cb] O^T accumulators
    #pragma unroll
    for (int ib = 0; ib < 2; ++ib)
        #pragma unroll
        for (int cb = 0; cb < 2; ++cb)
            #pragma unroll
            for (int r = 0; r < 16; ++r) o[ib][cb][r] = 0.f;
    f32x16 lacc[2];                      // denominator accumulators (ones-MFMA)
    #pragma unroll
    for (int ib = 0; ib < 2; ++ib)
        #pragma unroll
        for (int r = 0; r < 16; ++r) lacc[ib][r] = 0.f;

    // stage one j-tile (G rows j0..j0+63 [j][c], K rows c [c][j0..j0+63]) into lds[buf],
    // source pre-swizzled: slot ^= (row&7)  (16B slots within 128B rows)
    auto STAGE = [&](int buf, int j0) {
        #pragma unroll
        for (int r = 0; r < 4; ++r) {
            const int off = r * 4096 + wave * 1024 + lane * 16;
            const char* src;
            if (r < 2) {                                  // G region (bytes 0..8191)
                const int row = off >> 7, colb = off & 127;
                src = Gb + (size_t)(j0 + row) * 128 + (colb ^ ((row & 7) << 4));
            } else {                                      // K region (bytes 8192..16383)
                const int ok = off - 8192;
                const int row = ok >> 7, colb = ok & 127;
                src = Kb + (size_t)row * 8192 + (size_t)j0 * 2 + (colb ^ ((row & 7) << 4));
            }
            gload_lds16(src, lds[buf] + r * 4096 + wave * 1024);
        }
    };

    STAGE(0, jlo);
    __syncthreads();

    for (int t = 0; t < niter; ++t) {
        const int cur = t & 1;
        if (t + 1 < niter) STAGE(cur ^ 1, jlo + (t + 1) * 64);
        const char* L = lds[cur];

        short8 pf[2][4];                 // [ib][ks_global] P B-frags
        #pragma unroll
        for (int jb = 0; jb < 2; ++jb) {
            short8 ga[4];
            #pragma unroll
            for (int ks = 0; ks < 4; ++ks)
                ga[ks] = *(const short8*)(L + gaoff[jb][ks]);
            #pragma unroll
            for (int ib = 0; ib < 2; ++ib) {
                __builtin_amdgcn_s_setprio(1);
                f32x16 acc = __builtin_amdgcn_mfma_f32_32x32x16_bf16(ga[0], q[ib][0], zacc, 0, 0, 0);
                acc = __builtin_amdgcn_mfma_f32_32x32x16_bf16(ga[1], q[ib][1], acc, 0, 0, 0);
                acc = __builtin_amdgcn_mfma_f32_32x32x16_bf16(ga[2], q[ib][2], acc, 0, 0, 0);
                acc = __builtin_amdgcn_mfma_f32_32x32x16_bf16(ga[3], q[ib][3], acc, 0, 0, 0);
                __builtin_amdgcn_s_setprio(0);
                // P = 2^acc (lane-local row i = lane&31)
                float p[16];
                #pragma unroll
                for (int r = 0; r < 16; ++r) p[r] = exp2f(acc[r]);
                // pack to PV B-frags: k=j needs lane(hi) to hold j=16ks'+8hi+t.
                // p[r] holds j_local = (r&3)+8*(r>>2)+4hi. Two permlane32_swaps
                // per kstep redistribute the hi-halves (T12).
                #pragma unroll
                for (int kk = 0; kk < 2; ++kk) {
                    unsigned int x0 = cvtpk_bf16(p[8 * kk + 0], p[8 * kk + 1]);
                    unsigned int x1 = cvtpk_bf16(p[8 * kk + 2], p[8 * kk + 3]);
                    unsigned int y0 = cvtpk_bf16(p[8 * kk + 4], p[8 * kk + 5]);
                    unsigned int y1 = cvtpk_bf16(p[8 * kk + 6], p[8 * kk + 7]);
                    asm volatile("v_permlane32_swap_b32 %0, %1" : "+v"(x0), "+v"(y0));
                    asm volatile("v_permlane32_swap_b32 %0, %1" : "+v"(x1), "+v"(y1));
                    union { unsigned int u[4]; short8 v; } w;
                    w.u[0] = x0; w.u[1] = x1; w.u[2] = y0; w.u[3] = y1;
                    pf[ib][2 * jb + kk] = w.v;
                }
            }
        }

        // PV: O^T[c][i] += K[c][j] * P[i][j];  L[i] += sum_j P[i][j] (ones-MFMA)
        __builtin_amdgcn_s_setprio(1);
        #pragma unroll
        for (int ks = 0; ks < 4; ++ks) {
            const short8 ka0 = *(const short8*)(L + kaoff[0][ks]);
            const short8 ka1 = *(const short8*)(L + kaoff[1][ks]);
            #pragma unroll
            for (int ib = 0; ib < 2; ++ib) {
                o[ib][0]  = __builtin_amdgcn_mfma_f32_32x32x16_bf16(ka0, pf[ib][ks], o[ib][0], 0, 0, 0);
                o[ib][1]  = __builtin_amdgcn_mfma_f32_32x32x16_bf16(ka1, pf[ib][ks], o[ib][1], 0, 0, 0);
                lacc[ib]  = __builtin_amdgcn_mfma_f32_32x32x16_bf16(ones, pf[ib][ks], lacc[ib], 0, 0, 0);
            }
        }
        __builtin_amdgcn_s_setprio(0);
        __syncthreads();   // drains staging vmcnt + all waves done reading cur
    }

    // epilogue: O^T is already channel-major -> coalesced dword stores
    const size_t pb = (size_t)(b * split + sp);
    #pragma unroll
    for (int ib = 0; ib < 2; ++ib) {
        #pragma unroll
        for (int cb = 0; cb < 2; ++cb)
            #pragma unroll
            for (int r = 0; r < 16; ++r) {
                const int c = cb * 32 + (r & 3) + 8 * (r >> 2) + 4 * hi;
                const int i = i0w + ib * 32 + l32;
                Opart[(pb * CCH + c) * NPIX + i] = o[ib][cb][r];
            }
        // lacc rows are all identical (ones A): any reg holds L[i] for i=lane&31
        if (lane < 32)
            Lpart[pb * NPIX + i0w + ib * 32 + l32] = lacc[ib][0];
    }
}

// ---------------------------------------------------------------------------
// Kernel 3: combine split partials: out[b][c][i] = sum_sp O / sum_sp L + x
// (Opart is channel-major like x/out: no transpose needed.)
// ---------------------------------------------------------------------------
__global__ __launch_bounds__(256) void combine_kernel(
    const float* __restrict__ Opart, const float* __restrict__ Lpart,
    const float* __restrict__ x, float* __restrict__ out, int split)
{
    const int b = blockIdx.x >> 6, c = blockIdx.x & 63;
    for (int i = threadIdx.x * 4; i < NPIX; i += 1024) {
        f32x4 acc = (f32x4){0.f, 0.f, 0.f, 0.f};
        f32x4 Ls  = (f32x4){0.f, 0.f, 0.f, 0.f};
        for (int s = 0; s < split; ++s) {
            const size_t pb = (size_t)(b * split + s);
            acc += *(const f32x4*)&Opart[(pb * CCH + c) * NPIX + i];
            Ls  += *(const f32x4*)&Lpart[pb * NPIX + i];
        }
        const size_t idx = ((size_t)b * CCH + c) * NPIX + i;
        const f32x4 xv = *(const f32x4*)&x[idx];
        f32x4 r;
        #pragma unroll
        for (int t = 0; t < 4; ++t) r[t] = acc[t] / Ls[t] + xv[t];
        *(f32x4*)&out[idx] = r;
    }
}

extern "C" void kernel_launch(void* const* d_in, const int* in_sizes, int n_in,
                              void* d_out, int out_size, void* d_ws, size_t ws_size,
                              hipStream_t stream) {
    const float* x  = (const float*)d_in[0];
    const float* W1 = (const float*)d_in[1];
    const float* b1 = (const float*)d_in[2];
    const float* W2 = (const float*)d_in[3];
    const float* b2 = (const float*)d_in[4];
    const float* W3 = (const float*)d_in[5];
    const float* b3 = (const float*)d_in[6];
    float* out = (float*)d_out;

    char* ws = (char*)d_ws;
    const size_t planeB = (size_t)NB * NPIX * CCH * sizeof(__hip_bfloat16); // 4 MB
    __hip_bfloat16* Q = (__hip_bfloat16*)(ws);
    __hip_bfloat16* G = (__hip_bfloat16*)(ws + planeB);
    __hip_bfloat16* K = (__hip_bfloat16*)(ws + 2 * planeB);

    const size_t base   = 3 * planeB;                               // 12 MB
    const size_t oPlane = (size_t)NB * NPIX * CCH * sizeof(float);  // 8 MB per split
    const size_t lPlane = (size_t)NB * NPIX * sizeof(float);        // 128 KB per split

    int split = 4;
    while (split > 1 && base + (size_t)split * (oPlane + lPlane) > ws_size)
        split >>= 1;

    float* Opart = (float*)(ws + base);
    float* Lpart = (float*)(ws + base + (size_t)split * oPlane);

    proj_kernel<<<dim3(NB * 64), dim3(256), 0, stream>>>(x, W1, b1, W2, b2, W3, b3, Q, G, K);
    attn_kernel<<<dim3(NB * 16 * split), dim3(256), 0, stream>>>(Q, G, K, Opart, Lpart, split);
    combine_kernel<<<dim3(NB * CCH), dim3(256), 0, stream>>>(Opart, Lpart, x, out, split);
}

// Round 5
// 89.893 us; speedup vs baseline: 1.0578x; 1.0578x over previous
//
#include <hip/hip_runtime.h>
#include <hip/hip_bf16.h>

#define NPIX 4096   // 64*64 pixels per batch
#define CCH  64     // channels
#define NB   8      // batch
#define KVBLK 128   // j-tile per pipeline stage

typedef __attribute__((ext_vector_type(8)))  short short8;   // 8 bf16 MFMA A/B frag (32x32x16)
typedef __attribute__((ext_vector_type(4)))  float f32x4;
typedef __attribute__((ext_vector_type(16))) float f32x16;   // 32x32 MFMA C/D frag

#define LOG2E   1.44269504f

// ---------------------------------------------------------------------------
// Kernel 1: fused 1x1-conv projections.
//   Q[b][i][oc] = log2e * (W1 x + b1)   (bf16 pixel-major; scaled for exp2)
//   G[b][j][oc] =         (W2 x + b2)   (bf16 pixel-major)
//   K[b][oc][j] =         (W3 x + b3)   (bf16 channel-major)
// ---------------------------------------------------------------------------
__global__ __launch_bounds__(256) void proj_kernel(
    const float* __restrict__ x,
    const float* __restrict__ W1, const float* __restrict__ b1,
    const float* __restrict__ W2, const float* __restrict__ b2,
    const float* __restrict__ W3, const float* __restrict__ b3,
    __hip_bfloat16* __restrict__ Q, __hip_bfloat16* __restrict__ G,
    __hip_bfloat16* __restrict__ K)
{
    const int b  = blockIdx.x >> 6;
    const int i0 = (blockIdx.x & 63) << 6;

    __shared__ float xs[64][65];
    __shared__ float Wt[3][64][68];

    for (int e = threadIdx.x; e < 4096; e += 256) {
        const int c = e >> 6, p = e & 63;
        xs[c][p] = x[(size_t)b * CCH * NPIX + (size_t)c * NPIX + i0 + p];
        Wt[0][e & 63][e >> 6] = W1[e];
        Wt[1][e & 63][e >> 6] = W2[e];
        Wt[2][e & 63][e >> 6] = W3[e];
    }
    __syncthreads();

    const int p = threadIdx.x & 63;
    const int g = threadIdx.x >> 6;

    float acc0[16], acc1[16], acc2[16];
    #pragma unroll
    for (int oo = 0; oo < 16; ++oo) {
        acc0[oo] = b1[g * 16 + oo];
        acc1[oo] = b2[g * 16 + oo];
        acc2[oo] = b3[g * 16 + oo];
    }

    for (int c = 0; c < 64; ++c) {
        const float xv = xs[c][p];
        const f32x4* w0 = (const f32x4*)&Wt[0][c][g * 16];
        const f32x4* w1 = (const f32x4*)&Wt[1][c][g * 16];
        const f32x4* w2 = (const f32x4*)&Wt[2][c][g * 16];
        #pragma unroll
        for (int q = 0; q < 4; ++q) {
            const f32x4 a = w0[q], bb = w1[q], cc = w2[q];
            #pragma unroll
            for (int j = 0; j < 4; ++j) {
                acc0[q * 4 + j] += a[j] * xv;
                acc1[q * 4 + j] += bb[j] * xv;
                acc2[q * 4 + j] += cc[j] * xv;
            }
        }
    }

    const int i = i0 + p;
    #pragma unroll
    for (int oo = 0; oo < 16; ++oo) {
        const int oc = g * 16 + oo;
        Q[(size_t)b * NPIX * CCH + (size_t)i * CCH + oc] = __float2bfloat16(acc0[oo] * LOG2E);
        G[(size_t)b * NPIX * CCH + (size_t)i * CCH + oc] = __float2bfloat16(acc1[oo]);
        K[(size_t)b * CCH * NPIX + (size_t)oc * NPIX + i] = __float2bfloat16(acc2[oo]);
    }
}

// ---------------------------------------------------------------------------
// Kernel 2: LDS-staged flash attention, 32x32x16 MFMA, swapped QK^T, KVBLK=128
// per-jb fused pipeline: QK -> exp2 -> pack (cvt_pk+permlane32_swap) -> PV.
// No softmax shift (cancels in normalization; f32/bf16 range is ample).
// Block: 4 waves x 64 rows = 256 Q-rows; j-tiles of 128, double-buffered LDS.
// 32x32x16 bf16 layouts (m74/m101-verified C/D; A/B contiguous-8k):
//   A: row=lane&31, k=8*(lane>>5)+t     B: col=lane&31, k=8*(lane>>5)+t
//   C/D: col=lane&31, row=(r&3)+8*(r>>2)+4*(lane>>5)
// LDS per buf: G[128 rows][128B] swz ^(row&7), K[64 rows][256B] swz ^(row&15).
// ---------------------------------------------------------------------------
__device__ __forceinline__ void gload_lds16(const void* g, void* l) {
    __builtin_amdgcn_global_load_lds(
        (const __attribute__((address_space(1))) unsigned int*)g,
        (__attribute__((address_space(3))) unsigned int*)l, 16, 0, 0);
}
__device__ __forceinline__ unsigned int cvtpk_bf16(float lo, float hi) {
    unsigned int r;
    asm volatile("v_cvt_pk_bf16_f32 %0, %1, %2" : "=v"(r) : "v"(lo), "v"(hi));
    return r;
}

__global__ __launch_bounds__(256, 2) void attn_kernel(
    const __hip_bfloat16* __restrict__ Qg, const __hip_bfloat16* __restrict__ Gg,
    const __hip_bfloat16* __restrict__ Kg,
    __hip_bfloat16* __restrict__ Opart, float* __restrict__ Lpart, int split)
{
    __shared__ char lds[2][32768];      // [buf][ G 16KB | K 16KB ], XOR-swizzled

    const int blk   = blockIdx.x;
    const int per_b = 16 * split;
    const int b     = blk / per_b;
    const int rem   = blk - b * per_b;
    const int itile = rem / split;
    const int sp    = rem - itile * split;
    const int wave  = threadIdx.x >> 6;
    const int lane  = threadIdx.x & 63;
    const int l32   = lane & 31;
    const int hi    = lane >> 5;
    const int i0w   = itile * 256 + wave * 64;    // wave's first of 64 rows
    const int jcnt  = NPIX / split;
    const int jlo   = sp * jcnt;
    const int niter = jcnt / KVBLK;

    const short* Qb = (const short*)Qg + (size_t)b * NPIX * CCH;
    const char*  Gb = (const char*)(Gg + (size_t)b * NPIX * CCH);
    const char*  Kb = (const char*)(Kg + (size_t)b * CCH * NPIX);

    // Q B-frags: q[ib][ks] -> Q[i0w+ib*32+l32][16ks+8hi+t]
    short8 q[2][4];
    #pragma unroll
    for (int ib = 0; ib < 2; ++ib)
        #pragma unroll
        for (int ks = 0; ks < 4; ++ks)
            q[ib][ks] = *(const short8*)(Qb + (size_t)(i0w + ib * 32 + l32) * CCH + ks * 16 + hi * 8);

    // hoisted per-lane LDS read bases; per-read addr = base ^ (const<<4)
    // G: base holds row*128 | (row&7)<<4   (slot const = 2ks+hi <= 7, bits 4-6)
    // K: base holds 16384 + row*256 | (row&15)<<4  (slot const = 2ksg+hi <= 15, bits 4-7)
    int gbase[4], kbase[2];
    #pragma unroll
    for (int jb = 0; jb < 4; ++jb)
        gbase[jb] = (jb * 32 + l32) * 128 + ((l32 & 7) << 4);
    #pragma unroll
    for (int cb = 0; cb < 2; ++cb)
        kbase[cb] = 16384 + (cb * 32 + l32) * 256 + ((l32 & 15) << 4);

    // hoisted per-lane staging source pointers (iter t adds t*16384 / t*256)
    const char* gsrc[4]; const char* ksrc[4];
    #pragma unroll
    for (int r = 0; r < 4; ++r) {
        {   // G half: 16KB, rows of 128B
            const int off = r * 4096 + wave * 1024 + lane * 16;
            const int row = off >> 7, colb = off & 127;
            gsrc[r] = Gb + (size_t)(jlo + row) * 128 + (colb ^ ((row & 7) << 4));
        }
        {   // K half: 16KB, rows of 256B (c-major, j window)
            const int ok = r * 4096 + wave * 1024 + lane * 16;
            const int row = ok >> 8, colb = ok & 255;
            ksrc[r] = Kb + (size_t)row * 8192 + (size_t)jlo * 2 + (colb ^ ((row & 15) << 4));
        }
    }

    f32x16 zacc;
    #pragma unroll
    for (int r = 0; r < 16; ++r) zacc[r] = 0.f;
    short8 ones;
    #pragma unroll
    for (int t = 0; t < 8; ++t) ones[t] = (short)0x3F80;   // bf16 1.0

    f32x16 o[2][2];                      // [ib][cb] O^T accumulators
    #pragma unroll
    for (int ib = 0; ib < 2; ++ib)
        #pragma unroll
        for (int cb = 0; cb < 2; ++cb)
            #pragma unroll
            for (int r = 0; r < 16; ++r) o[ib][cb][r] = 0.f;
    f32x16 lacc[2];                      // denominator accumulators (ones-MFMA)
    #pragma unroll
    for (int ib = 0; ib < 2; ++ib)
        #pragma unroll
        for (int r = 0; r < 16; ++r) lacc[ib][r] = 0.f;

    auto STAGE = [&](int buf, int tt) {
        #pragma unroll
        for (int r = 0; r < 4; ++r)
            gload_lds16(gsrc[r] + tt * (KVBLK * 128), lds[buf] + r * 4096 + wave * 1024);
        #pragma unroll
        for (int r = 0; r < 4; ++r)
            gload_lds16(ksrc[r] + tt * (KVBLK * 2), lds[buf] + 16384 + r * 4096 + wave * 1024);
    };

    STAGE(0, 0);
    __syncthreads();

    for (int t = 0; t < niter; ++t) {
        const int cur = t & 1;
        STAGE(cur ^ 1, (t + 1 < niter) ? t + 1 : 0);   // uniform 8 loads (tail re-stages tile 0)
        const char* L = lds[cur];

        #pragma unroll
        for (int jb = 0; jb < 4; ++jb) {
            short8 ga[4];
            #pragma unroll
            for (int ks = 0; ks < 4; ++ks)
                ga[ks] = *(const short8*)(L + (gbase[jb] ^ ((2 * ks + hi) << 4)));

            short8 pf[2][2];             // [ib][kk]
            #pragma unroll
            for (int ib = 0; ib < 2; ++ib) {
                __builtin_amdgcn_s_setprio(1);
                f32x16 acc = __builtin_amdgcn_mfma_f32_32x32x16_bf16(ga[0], q[ib][0], zacc, 0, 0, 0);
                acc = __builtin_amdgcn_mfma_f32_32x32x16_bf16(ga[1], q[ib][1], acc, 0, 0, 0);
                acc = __builtin_amdgcn_mfma_f32_32x32x16_bf16(ga[2], q[ib][2], acc, 0, 0, 0);
                acc = __builtin_amdgcn_mfma_f32_32x32x16_bf16(ga[3], q[ib][3], acc, 0, 0, 0);
                __builtin_amdgcn_s_setprio(0);
                float p[16];
                #pragma unroll
                for (int r = 0; r < 16; ++r) p[r] = exp2f(acc[r]);
                // pack: p[r] holds j_local=(r&3)+8*(r>>2)+4hi; PV B-frag needs
                // lane(hi) to hold j=16kk'+8hi+t. cvt_pk pairs + permlane32_swap (T12).
                #pragma unroll
                for (int kk = 0; kk < 2; ++kk) {
                    unsigned int x0 = cvtpk_bf16(p[8 * kk + 0], p[8 * kk + 1]);
                    unsigned int x1 = cvtpk_bf16(p[8 * kk + 2], p[8 * kk + 3]);
                    unsigned int y0 = cvtpk_bf16(p[8 * kk + 4], p[8 * kk + 5]);
                    unsigned int y1 = cvtpk_bf16(p[8 * kk + 6], p[8 * kk + 7]);
                    asm volatile("v_permlane32_swap_b32 %0, %1" : "+v"(x0), "+v"(y0));
                    asm volatile("v_permlane32_swap_b32 %0, %1" : "+v"(x1), "+v"(y1));
                    union { unsigned int u[4]; short8 v; } w;
                    w.u[0] = x0; w.u[1] = x1; w.u[2] = y0; w.u[3] = y1;
                    pf[ib][kk] = w.v;
                }
            }

            // PV for this jb's two k-slices (ksg = 2jb+kk)
            __builtin_amdgcn_s_setprio(1);
            #pragma unroll
            for (int kk = 0; kk < 2; ++kk) {
                const int ksg = 2 * jb + kk;
                const short8 ka0 = *(const short8*)(L + (kbase[0] ^ ((2 * ksg + hi) << 4)));
                const short8 ka1 = *(const short8*)(L + (kbase[1] ^ ((2 * ksg + hi) << 4)));
                #pragma unroll
                for (int ib = 0; ib < 2; ++ib) {
                    o[ib][0] = __builtin_amdgcn_mfma_f32_32x32x16_bf16(ka0, pf[ib][kk], o[ib][0], 0, 0, 0);
                    o[ib][1] = __builtin_amdgcn_mfma_f32_32x32x16_bf16(ka1, pf[ib][kk], o[ib][1], 0, 0, 0);
                    lacc[ib] = __builtin_amdgcn_mfma_f32_32x32x16_bf16(ones, pf[ib][kk], lacc[ib], 0, 0, 0);
                }
            }
            __builtin_amdgcn_s_setprio(0);
        }
        __syncthreads();   // drains staging vmcnt + all waves done reading cur
    }

    // epilogue: O^T is channel-major -> coalesced bf16 stores
    const size_t pb = (size_t)(b * split + sp);
    #pragma unroll
    for (int ib = 0; ib < 2; ++ib) {
        #pragma unroll
        for (int cb = 0; cb < 2; ++cb)
            #pragma unroll
            for (int r = 0; r < 16; ++r) {
                const int c = cb * 32 + (r & 3) + 8 * (r >> 2) + 4 * hi;
                const int i = i0w + ib * 32 + l32;
                Opart[(pb * CCH + c) * NPIX + i] = __float2bfloat16(o[ib][cb][r]);
            }
        // lacc rows identical (ones A): reg 0 holds L[i] for i=lane&31
        if (lane < 32)
            Lpart[pb * NPIX + i0w + ib * 32 + l32] = lacc[ib][0];
    }
}

// ---------------------------------------------------------------------------
// Kernel 3: combine split partials: out[b][c][i] = sum_sp O / sum_sp L + x
// (Opart bf16, channel-major like x/out: no transpose needed.)
// ---------------------------------------------------------------------------
__global__ __launch_bounds__(256) void combine_kernel(
    const __hip_bfloat16* __restrict__ Opart, const float* __restrict__ Lpart,
    const float* __restrict__ x, float* __restrict__ out, int split)
{
    const int b = blockIdx.x >> 6, c = blockIdx.x & 63;
    #pragma unroll
    for (int chunk = 0; chunk < 2; ++chunk) {
        const int i = chunk * 2048 + threadIdx.x * 8;
        float acc[8] = {0,0,0,0,0,0,0,0};
        float Ls[8]  = {0,0,0,0,0,0,0,0};
        for (int s = 0; s < split; ++s) {
            const size_t pb = (size_t)(b * split + s);
            const short8 ov = *(const short8*)((const short*)Opart + (pb * CCH + c) * NPIX + i);
            const f32x4 l0 = *(const f32x4*)&Lpart[pb * NPIX + i];
            const f32x4 l1 = *(const f32x4*)&Lpart[pb * NPIX + i + 4];
            #pragma unroll
            for (int t = 0; t < 8; ++t) {
                union { unsigned int u; float f; } cv;
                cv.u = ((unsigned int)(unsigned short)ov[t]) << 16;
                acc[t] += cv.f;
                Ls[t]  += (t < 4) ? l0[t] : l1[t - 4];
            }
        }
        const size_t idx = ((size_t)b * CCH + c) * NPIX + i;
        const f32x4 xv0 = *(const f32x4*)&x[idx];
        const f32x4 xv1 = *(const f32x4*)&x[idx + 4];
        f32x4 r0, r1;
        #pragma unroll
        for (int t = 0; t < 4; ++t) {
            r0[t] = acc[t] / Ls[t] + xv0[t];
            r1[t] = acc[t + 4] / Ls[t + 4] + xv1[t];
        }
        *(f32x4*)&out[idx]     = r0;
        *(f32x4*)&out[idx + 4] = r1;
    }
}

extern "C" void kernel_launch(void* const* d_in, const int* in_sizes, int n_in,
                              void* d_out, int out_size, void* d_ws, size_t ws_size,
                              hipStream_t stream) {
    const float* x  = (const float*)d_in[0];
    const float* W1 = (const float*)d_in[1];
    const float* b1 = (const float*)d_in[2];
    const float* W2 = (const float*)d_in[3];
    const float* b2 = (const float*)d_in[4];
    const float* W3 = (const float*)d_in[5];
    const float* b3 = (const float*)d_in[6];
    float* out = (float*)d_out;

    char* ws = (char*)d_ws;
    const size_t planeB = (size_t)NB * NPIX * CCH * sizeof(__hip_bfloat16); // 4 MB
    __hip_bfloat16* Q = (__hip_bfloat16*)(ws);
    __hip_bfloat16* G = (__hip_bfloat16*)(ws + planeB);
    __hip_bfloat16* K = (__hip_bfloat16*)(ws + 2 * planeB);

    const size_t base   = 3 * planeB;                               // 12 MB
    const size_t oPlane = planeB;                                   // 4 MB per split (bf16)
    const size_t lPlane = (size_t)NB * NPIX * sizeof(float);        // 128 KB per split

    int split = 4;
    while (split > 1 && base + (size_t)split * (oPlane + lPlane) > ws_size)
        split >>= 1;

    __hip_bfloat16* Opart = (__hip_bfloat16*)(ws + base);
    float* Lpart = (float*)(ws + base + (size_t)split * oPlane);

    proj_kernel<<<dim3(NB * 64), dim3(256), 0, stream>>>(x, W1, b1, W2, b2, W3, b3, Q, G, K);
    attn_kernel<<<dim3(NB * 16 * split), dim3(256), 0, stream>>>(Q, G, K, Opart, Lpart, split);
    combine_kernel<<<dim3(NB * CCH), dim3(256), 0, stream>>>(Opart, Lpart, x, out, split);
}